// Round 1
// baseline (938.227 us; speedup 1.0000x reference)
//
#include <hip/hip_runtime.h>

constexpr int NT = 10;      // NTASKS
constexpr int CP = 8;       // CAP
constexpr int LLn = 256;    // L
constexpr int DI = 768;     // D_IN
constexpr int DD = 768;     // D_DOWN
constexpr int BB = 64;      // B
constexpr int BLr = BB * LLn;   // 16384
constexpr int RR = LLn * CP;    // 2048

// ---------------- K_W12: W12[t*8+c][i] = sum_d w1[t][d][i] * w2[t][c][d] ----------------
__global__ __launch_bounds__(256) void k_w12(const float* __restrict__ w1,
                                             const float* __restrict__ w2,
                                             float* __restrict__ w12) {
  const int t = blockIdx.y;
  const int i0 = blockIdx.x * 64;
  __shared__ float sW1[64][68];   // [d_local][i_local], stride 68 (16B-aligned, conflict-safe)
  __shared__ float sW2[CP][64];   // [c][d_local]
  const int tid = threadIdx.x;
  const int il = tid >> 2;        // 0..63
  const int cc = (tid & 3) * 2;   // c pair
  float a0 = 0.f, a1 = 0.f;
  for (int d0 = 0; d0 < DD; d0 += 64) {
#pragma unroll
    for (int p = 0; p < 4; p++) {
      int idx = p * 256 + tid;
      int dl = idx >> 4, c4 = (idx & 15) * 4;
      *(float4*)&sW1[dl][c4] =
          *(const float4*)(w1 + ((size_t)t * DD + d0 + dl) * DI + i0 + c4);
    }
    if (tid < 128) {
      int c = tid >> 4, d4 = (tid & 15) * 4;
      *(float4*)&sW2[c][d4] =
          *(const float4*)(w2 + ((size_t)t * CP + c) * DD + d0 + d4);
    }
    __syncthreads();
#pragma unroll 16
    for (int dl = 0; dl < 64; ++dl) {
      float v = sW1[dl][il];
      a0 += v * sW2[cc][dl];
      a1 += v * sW2[cc + 1][dl];
    }
    __syncthreads();
  }
  w12[((size_t)t * CP + cc) * DI + i0 + il]     = a0;
  w12[((size_t)t * CP + cc + 1) * DI + i0 + il] = a1;
}

// ---------------- K_B12: b12[t*8+c] = sum_d b1[t][d]*w2[t][c][d] + b2[t][c] ----------------
// One wave per tc; float4 loads + shuffle reduce. Grid = 20 blocks x 256.
__global__ __launch_bounds__(256) void k_b12(const float* __restrict__ b1,
                                             const float* __restrict__ w2,
                                             const float* __restrict__ b2,
                                             float* __restrict__ b12) {
  const int tc = blockIdx.x * 4 + (threadIdx.x >> 6);  // 0..79
  const int lane = threadIdx.x & 63;
  const int t = tc >> 3, c = tc & 7;
  const float* b1r = b1 + (size_t)t * DD;
  const float* w2r = w2 + ((size_t)t * CP + c) * DD;
  float s = 0.f;
  for (int d = lane * 4; d < DD; d += 256) {  // 3 iters
    float4 bv = *(const float4*)(b1r + d);
    float4 wv = *(const float4*)(w2r + d);
    s += bv.x * wv.x + bv.y * wv.y + bv.z * wv.z + bv.w * wv.w;
  }
#pragma unroll
  for (int st = 32; st > 0; st >>= 1) s += __shfl_xor(s, st, 64);
  if (lane == 0) b12[tc] = s + b2[t * CP + c];
}

// ---------------- K_FC: h2[t][m][c] = sum_i x[m][i]*W12[t*8+c][i] + b12 ----------------
// LDS-tiled fp32 GEMM: M=16384, N=80, K=768. BM=64, BK=64, 512 threads (8 waves/CU),
// double-buffered LDS (x + w12), reg-staged issue-early/write-late (T14).
// Thread tile: 2m x 5tc (tc = q + 16*kk). LDS rows padded to 68 floats (16B-aligned).
__global__ __launch_bounds__(512) void k_fc(const float* __restrict__ x,
                                            const float* __restrict__ w12,
                                            const float* __restrict__ b12,
                                            float* __restrict__ h2) {
  __shared__ float xs[2][64][68];   // 34.8 KB
  __shared__ float ws[2][80][68];   // 43.5 KB
  const int tid = threadIdx.x;
  const int m0 = blockIdx.x * 64;
  const int q  = tid & 15;          // tc = q + 16*kk, kk=0..4
  const int mg = tid >> 4;          // 0..31 -> m = m0 + 2*mg + {0,1}

  // staging mapping: granule g -> row = g>>4, col4 = g&15 (float4 along K)
  const int srow = tid >> 4;                 // 0..31
  const int scol = (tid & 15) * 4;
  const float* xg = x + (size_t)(m0 + srow) * DI + (tid & 15) * 4;
  const float* wg = w12 + (size_t)srow * DI + (tid & 15) * 4;

  float4 xr[2], wr[3];
  float acc0[5] = {}, acc1[5] = {};

  auto GLOAD = [&](int k0) {
    xr[0] = *(const float4*)(xg + k0);
    xr[1] = *(const float4*)(xg + (size_t)32 * DI + k0);
    wr[0] = *(const float4*)(wg + k0);
    wr[1] = *(const float4*)(wg + (size_t)32 * DI + k0);
    if (tid < 256) wr[2] = *(const float4*)(wg + (size_t)64 * DI + k0);
  };
  auto WRITE = [&](int buf) {
    *(float4*)&xs[buf][srow][scol]      = xr[0];
    *(float4*)&xs[buf][32 + srow][scol] = xr[1];
    *(float4*)&ws[buf][srow][scol]      = wr[0];
    *(float4*)&ws[buf][32 + srow][scol] = wr[1];
    if (tid < 256) *(float4*)&ws[buf][64 + srow][scol] = wr[2];
  };

  GLOAD(0);
  WRITE(0);
  __syncthreads();

  for (int s = 0; s < 12; ++s) {
    if (s < 11) GLOAD((s + 1) * 64);     // issue next-step loads early (latency hidden)
    const int buf = s & 1;
#pragma unroll
    for (int k4 = 0; k4 < 16; ++k4) {
      float4 xv0 = *(const float4*)&xs[buf][2 * mg + 0][k4 * 4];
      float4 xv1 = *(const float4*)&xs[buf][2 * mg + 1][k4 * 4];
#pragma unroll
      for (int kk = 0; kk < 5; ++kk) {
        float4 wv = *(const float4*)&ws[buf][q + 16 * kk][k4 * 4];
        acc0[kk] += xv0.x * wv.x + xv0.y * wv.y + xv0.z * wv.z + xv0.w * wv.w;
        acc1[kk] += xv1.x * wv.x + xv1.y * wv.y + xv1.z * wv.z + xv1.w * wv.w;
      }
    }
    if (s < 11) {
      WRITE((s + 1) & 1);                // vmcnt drain happens here, after compute
      __syncthreads();
    }
  }

#pragma unroll
  for (int kk = 0; kk < 5; ++kk) {
    int tc = q + 16 * kk;
    int t = tc >> 3, c = tc & 7;
    float bv = b12[tc];
    size_t base = ((size_t)t * BLr + m0 + 2 * mg) * CP + c;
    h2[base]      = acc0[kk] + bv;
    h2[base + CP] = acc1[kk] + bv;
  }
}

// ---------------- K2: squash over task dim -> sems[t][b][r] (t<=et) ----------------
__global__ __launch_bounds__(256) void k_squash_sem(const float* __restrict__ h2,
                                                    const int* __restrict__ etp,
                                                    float* __restrict__ sems) {
  int et = *etp;
  int i = blockIdx.x * 256 + threadIdx.x;  // i = b*2048 + r
  if (i >= BB * RR) return;
  float v[NT];
  float sq = 0.f;
#pragma unroll
  for (int t = 0; t < NT; ++t) {
    v[t] = h2[(size_t)t * BB * RR + i];
    sq += v[t] * v[t];
  }
  sq += 1e-16f;
  float scale = (sq / (1.f + sq)) * rsqrtf(sq);
#pragma unroll
  for (int t = 0; t < NT; ++t)
    if (t <= et) sems[(size_t)t * BB * RR + i] = scale * v[t];
}

// ---------------- K3: priors[c][t][b][o] = sum_r sems[t][b][r] * rw[c][t][r][o] ----------------
constexpr int OT = 64;  // o tile
constexpr int RK = 64;  // r chunk
__global__ __launch_bounds__(256) void k_priors(const float* __restrict__ sems,
                                                const float* __restrict__ rw,
                                                const int* __restrict__ etp,
                                                float* __restrict__ priors) {
  int et = *etp;
  int t = blockIdx.y;
  if (t > et) return;
  int c2 = blockIdx.z;
  int o0 = blockIdx.x * OT;
  int tid = threadIdx.x;
  __shared__ float semT[RK][BB + 4];  // [r][b]
  __shared__ float rwS[RK][OT + 4];   // [r][o]
  int og = (tid & 15) * 4;  // o offset in tile
  int bg = (tid >> 4) * 4;  // b offset
  float acc[4][4] = {};
  for (int r0 = 0; r0 < RR; r0 += RK) {
#pragma unroll
    for (int p = 0; p < 4; p++) {  // sems: float4 along r, store transposed
      int idx = p * 256 + tid;
      int b = idx >> 4;
      int r4 = (idx & 15) * 4;
      float4 v = *(const float4*)(sems + ((size_t)t * BB + b) * RR + r0 + r4);
      semT[r4 + 0][b] = v.x; semT[r4 + 1][b] = v.y;
      semT[r4 + 2][b] = v.z; semT[r4 + 3][b] = v.w;
    }
#pragma unroll
    for (int p = 0; p < 4; p++) {  // rw rows are o-contiguous
      int idx = p * 256 + tid;
      int r = idx >> 4;
      int o4 = (idx & 15) * 4;
      *(float4*)&rwS[r][o4] =
          *(const float4*)(rw + ((size_t)(c2 * NT + t) * RR + r0 + r) * LLn + o0 + o4);
    }
    __syncthreads();
#pragma unroll 8
    for (int r = 0; r < RK; ++r) {
      float4 a = *(const float4*)&semT[r][bg];
      float4 w = *(const float4*)&rwS[r][og];
#pragma unroll
      for (int i = 0; i < 4; i++)
#pragma unroll
        for (int j = 0; j < 4; j++) acc[i][j] += a[i] * w[j];
    }
    __syncthreads();
  }
#pragma unroll
  for (int i = 0; i < 4; i++)
#pragma unroll
    for (int j = 0; j < 4; j++)
      priors[((size_t)(c2 * NT + t) * BB + bg + i) * LLn + o0 + og + j] = acc[i][j];
}

// ---------------- K4: dynamic routing — one wave per (b,c), barrier-free ----------------
// logits are uniform over o, so per-(b,c) state is {Lg[t]} scalars (uniform across lanes).
// Each lane holds 4 o-values (o = j*64 + lane); all reductions via __shfl_xor over 64 lanes.
// Register arrays are indexed only by compile-time t (full-NT unroll, t<=et predicated).
__global__ __launch_bounds__(64) void k_route(const float* __restrict__ priors,
                                              const int* __restrict__ etp,
                                              float* __restrict__ h) {
  const int et = *etp;
  const int b = blockIdx.x >> 3;
  const int c2 = blockIdx.x & 7;
  const int lane = threadIdx.x;  // 0..63

  float pri[NT][4];
#pragma unroll
  for (int t = 0; t < NT; ++t) {
    if (t <= et) {
#pragma unroll
      for (int j = 0; j < 4; ++j)
        pri[t][j] = priors[((size_t)(c2 * NT + t) * BB + b) * LLn + j * 64 + lane];
    } else {
#pragma unroll
      for (int j = 0; j < 4; ++j) pri[t][j] = 0.f;
    }
  }

  float Lg[NT];
#pragma unroll
  for (int t = 0; t < NT; ++t) Lg[t] = 0.f;
  float vote[4] = {};

  for (int it = 0; it < 3; ++it) {
    // softmax over active tasks (Lg uniform across lanes -> scalar math)
    float mx = -1e30f;
#pragma unroll
    for (int t = 0; t < NT; ++t)
      if (t <= et) mx = fmaxf(mx, Lg[t]);
    float p[NT];
    float s = 0.f;
#pragma unroll
    for (int t = 0; t < NT; ++t) {
      p[t] = (t <= et) ? __expf(Lg[t] - mx) : 0.f;
      s += p[t];
    }
    float inv = 1.f / s;
#pragma unroll
    for (int j = 0; j < 4; ++j) vote[j] = 0.f;
#pragma unroll
    for (int t = 0; t < NT; ++t) {
      if (t <= et) {
        float w = p[t] * inv;
#pragma unroll
        for (int j = 0; j < 4; ++j) vote[j] += w * pri[t][j];
      }
    }
    if (it == 2) break;

    // squash scale: sq = sum_o vote^2 (wave reduce)
    float sq = vote[0] * vote[0] + vote[1] * vote[1] + vote[2] * vote[2] + vote[3] * vote[3];
#pragma unroll
    for (int st = 32; st > 0; st >>= 1) sq += __shfl_xor(sq, st, 64);
    sq += 1e-16f;
    float scale = (sq / (1.f + sq)) * rsqrtf(sq);

    // Lg[t] += scale * sum_o pri[t][o]*vote[o]
#pragma unroll
    for (int t = 0; t < NT; ++t) {
      if (t <= et) {
        float dot = pri[t][0] * vote[0] + pri[t][1] * vote[1] +
                    pri[t][2] * vote[2] + pri[t][3] * vote[3];
#pragma unroll
        for (int st = 32; st > 0; st >>= 1) dot += __shfl_xor(dot, st, 64);
        Lg[t] += scale * dot;
      }
    }
  }

#pragma unroll
  for (int j = 0; j < 4; ++j)
    h[((size_t)c2 * BB + b) * LLn + j * 64 + lane] = vote[j];
}

// ---------------- K5: out[b,l,d] = sum_c h[b,l,c]*lw[et][d][c] + lb[et][d] ----------------
__global__ __launch_bounds__(256) void k_out(const float* __restrict__ h,
                                             const float* __restrict__ lw,
                                             const float* __restrict__ lb,
                                             const int* __restrict__ etp,
                                             float* __restrict__ out) {
  int et = *etp;
  int row = blockIdx.x;  // b2*256 + l
  const float* hr = h + (size_t)row * CP;
  float hv[CP];
#pragma unroll
  for (int c = 0; c < CP; ++c) hv[c] = hr[c];
  const float* lwb = lw + (size_t)et * DD * CP;
  const float* lbb = lb + (size_t)et * DD;
  for (int d = threadIdx.x; d < DD; d += 256) {
    const float* w = lwb + (size_t)d * CP;
    float s2 = lbb[d];
#pragma unroll
    for (int c = 0; c < CP; ++c) s2 += hv[c] * w[c];
    out[(size_t)row * DD + d] = s2;
  }
}

extern "C" void kernel_launch(void* const* d_in, const int* in_sizes, int n_in,
                              void* d_out, int out_size, void* d_ws, size_t ws_size,
                              hipStream_t stream) {
  const float* x  = (const float*)d_in[0];
  const float* w1 = (const float*)d_in[1];
  const float* b1 = (const float*)d_in[2];
  const float* w2 = (const float*)d_in[3];
  const float* b2 = (const float*)d_in[4];
  const float* rw = (const float*)d_in[5];
  const float* lw = (const float*)d_in[6];
  const float* lb = (const float*)d_in[7];
  const int* etp  = (const int*)d_in[8];
  float* out = (float*)d_out;

  char* ws = (char*)d_ws;
  size_t off = 0;
  auto alloc = [&](size_t bytes) {
    void* p = ws + off;
    off = (off + bytes + 255) & ~(size_t)255;
    return p;
  };
  float* w12   = (float*)alloc((size_t)NT * CP * DI * 4);        // 245 KB
  float* b12   = (float*)alloc((size_t)NT * CP * 4);             // 320 B
  float* h2    = (float*)alloc((size_t)NT * BLr * CP * 4);       // 5.24 MB
  float* sems  = (float*)alloc((size_t)NT * BB * RR * 4);        // 5.24 MB
  float* priors= (float*)alloc((size_t)CP * NT * BB * LLn * 4);  // 5.24 MB
  float* hbuf  = (float*)alloc((size_t)CP * BB * LLn * 4);       // 0.52 MB

  k_w12<<<dim3(DI / 64, NT), 256, 0, stream>>>(w1, w2, w12);
  k_b12<<<20, 256, 0, stream>>>(b1, w2, b2, b12);
  k_fc<<<BLr / 64, 512, 0, stream>>>(x, w12, b12, h2);
  k_squash_sem<<<(BB * RR + 255) / 256, 256, 0, stream>>>(h2, etp, sems);
  k_priors<<<dim3(LLn / OT, NT, CP), 256, 0, stream>>>(sems, rw, etp, priors);
  k_route<<<BB * CP, 64, 0, stream>>>(priors, etp, hbuf);
  k_out<<<BLr, 256, 0, stream>>>(hbuf, lw, lb, etp, out);
}

// Round 3
// 873.281 us; speedup vs baseline: 1.0744x; 1.0744x over previous
//
#include <hip/hip_runtime.h>

constexpr int NT = 10;      // NTASKS
constexpr int CP = 8;       // CAP
constexpr int LLn = 256;    // L
constexpr int DI = 768;     // D_IN
constexpr int DD = 768;     // D_DOWN
constexpr int BB = 64;      // B
constexpr int BLr = BB * LLn;   // 16384
constexpr int RR = LLn * CP;    // 2048

// ---------------- K_W12: W12[t*8+c][i] = sum_d w1[t][d][i] * w2[t][c][d] ----------------
__global__ __launch_bounds__(256) void k_w12(const float* __restrict__ w1,
                                             const float* __restrict__ w2,
                                             float* __restrict__ w12) {
  const int t = blockIdx.y;
  const int i0 = blockIdx.x * 64;
  __shared__ float sW1[64][68];   // [d_local][i_local], stride 68 (16B-aligned, conflict-safe)
  __shared__ float sW2[CP][64];   // [c][d_local]
  const int tid = threadIdx.x;
  const int il = tid >> 2;        // 0..63
  const int cc = (tid & 3) * 2;   // c pair
  float a0 = 0.f, a1 = 0.f;
  for (int d0 = 0; d0 < DD; d0 += 64) {
#pragma unroll
    for (int p = 0; p < 4; p++) {
      int idx = p * 256 + tid;
      int dl = idx >> 4, c4 = (idx & 15) * 4;
      *(float4*)&sW1[dl][c4] =
          *(const float4*)(w1 + ((size_t)t * DD + d0 + dl) * DI + i0 + c4);
    }
    if (tid < 128) {
      int c = tid >> 4, d4 = (tid & 15) * 4;
      *(float4*)&sW2[c][d4] =
          *(const float4*)(w2 + ((size_t)t * CP + c) * DD + d0 + d4);
    }
    __syncthreads();
#pragma unroll 16
    for (int dl = 0; dl < 64; ++dl) {
      float v = sW1[dl][il];
      a0 += v * sW2[cc][dl];
      a1 += v * sW2[cc + 1][dl];
    }
    __syncthreads();
  }
  w12[((size_t)t * CP + cc) * DI + i0 + il]     = a0;
  w12[((size_t)t * CP + cc + 1) * DI + i0 + il] = a1;
}

// ---------------- K_B12: b12[t*8+c] = sum_d b1[t][d]*w2[t][c][d] + b2[t][c] ----------------
__global__ __launch_bounds__(256) void k_b12(const float* __restrict__ b1,
                                             const float* __restrict__ w2,
                                             const float* __restrict__ b2,
                                             float* __restrict__ b12) {
  const int tc = blockIdx.x * 4 + (threadIdx.x >> 6);  // 0..79
  const int lane = threadIdx.x & 63;
  const int t = tc >> 3, c = tc & 7;
  const float* b1r = b1 + (size_t)t * DD;
  const float* w2r = w2 + ((size_t)t * CP + c) * DD;
  float s = 0.f;
  for (int d = lane * 4; d < DD; d += 256) {  // 3 iters
    float4 bv = *(const float4*)(b1r + d);
    float4 wv = *(const float4*)(w2r + d);
    s += bv.x * wv.x + bv.y * wv.y + bv.z * wv.z + bv.w * wv.w;
  }
#pragma unroll
  for (int st = 32; st > 0; st >>= 1) s += __shfl_xor(s, st, 64);
  if (lane == 0) b12[tc] = s + b2[t * CP + c];
}

// ---------------- K_FC: h2[t][m][c] = sum_i x[m][i]*W12[n][i] + b12 ----------------
// GEMM M=16384, N=80, K=768. No LDS, no barriers: w12 (240 KB) is L2-resident,
// x streams once. Thread = 1 m-row x 5 n (n = q + 16k). Block = 16 m-rows.
// Grid = 1024 blocks = 4 blocks/CU = 4 waves/SIMD — latency hidden by TLP
// (round-0 version was 1 wave/SIMD -> VALUBusy 13.5%).
__global__ __launch_bounds__(256) void k_fc(const float* __restrict__ x,
                                            const float* __restrict__ w12,
                                            const float* __restrict__ b12,
                                            float* __restrict__ h2) {
  const int m = blockIdx.x * 16 + (threadIdx.x >> 4);  // 16 m-rows per block
  const int q = threadIdx.x & 15;                      // n = q + 16*k, k=0..4
  const float4* xr = (const float4*)(x + (size_t)m * DI);
  const float4* wr = (const float4*)w12;
  float acc[5] = {};
#pragma unroll 2
  for (int i4 = 0; i4 < DI / 4; ++i4) {
    float4 xv = xr[i4];
#pragma unroll
    for (int k = 0; k < 5; ++k) {
      float4 wv = wr[(size_t)(q + 16 * k) * (DI / 4) + i4];
      acc[k] += xv.x * wv.x + xv.y * wv.y + xv.z * wv.z + xv.w * wv.w;
    }
  }
#pragma unroll
  for (int k = 0; k < 5; ++k) {
    int n = q + 16 * k;
    int t = n >> 3, c = n & 7;
    h2[((size_t)t * BLr + m) * CP + c] = acc[k] + b12[n];
  }
}

// ---------------- K2: squash over task dim -> sems[t][b][r] (t<=et) ----------------
__global__ __launch_bounds__(256) void k_squash_sem(const float* __restrict__ h2,
                                                    const int* __restrict__ etp,
                                                    float* __restrict__ sems) {
  int et = *etp;
  int i = blockIdx.x * 256 + threadIdx.x;  // i = b*2048 + r
  if (i >= BB * RR) return;
  float v[NT];
  float sq = 0.f;
#pragma unroll
  for (int t = 0; t < NT; ++t) {
    v[t] = h2[(size_t)t * BB * RR + i];
    sq += v[t] * v[t];
  }
  sq += 1e-16f;
  float scale = (sq / (1.f + sq)) * rsqrtf(sq);
#pragma unroll
  for (int t = 0; t < NT; ++t)
    if (t <= et) sems[(size_t)t * BB * RR + i] = scale * v[t];
}

// ---------------- K3: priors[c][t][b][o] = sum_r sems[t][b][r] * rw[c][t][r][o] ----------------
constexpr int OT = 64;  // o tile
constexpr int RK = 64;  // r chunk
__global__ __launch_bounds__(256) void k_priors(const float* __restrict__ sems,
                                                const float* __restrict__ rw,
                                                const int* __restrict__ etp,
                                                float* __restrict__ priors) {
  int et = *etp;
  int t = blockIdx.y;
  if (t > et) return;
  int c2 = blockIdx.z;
  int o0 = blockIdx.x * OT;
  int tid = threadIdx.x;
  __shared__ float semT[RK][BB + 4];  // [r][b]
  __shared__ float rwS[RK][OT + 4];   // [r][o]
  int og = (tid & 15) * 4;  // o offset in tile
  int bg = (tid >> 4) * 4;  // b offset
  float acc[4][4] = {};
  for (int r0 = 0; r0 < RR; r0 += RK) {
#pragma unroll
    for (int p = 0; p < 4; p++) {  // sems: float4 along r, store transposed
      int idx = p * 256 + tid;
      int b = idx >> 4;
      int r4 = (idx & 15) * 4;
      float4 v = *(const float4*)(sems + ((size_t)t * BB + b) * RR + r0 + r4);
      semT[r4 + 0][b] = v.x; semT[r4 + 1][b] = v.y;
      semT[r4 + 2][b] = v.z; semT[r4 + 3][b] = v.w;
    }
#pragma unroll
    for (int p = 0; p < 4; p++) {  // rw rows are o-contiguous
      int idx = p * 256 + tid;
      int r = idx >> 4;
      int o4 = (idx & 15) * 4;
      *(float4*)&rwS[r][o4] =
          *(const float4*)(rw + ((size_t)(c2 * NT + t) * RR + r0 + r) * LLn + o0 + o4);
    }
    __syncthreads();
#pragma unroll 8
    for (int r = 0; r < RK; ++r) {
      float4 a = *(const float4*)&semT[r][bg];
      float4 w = *(const float4*)&rwS[r][og];
#pragma unroll
      for (int i = 0; i < 4; i++)
#pragma unroll
        for (int j = 0; j < 4; j++) acc[i][j] += a[i] * w[j];
    }
    __syncthreads();
  }
#pragma unroll
  for (int i = 0; i < 4; i++)
#pragma unroll
    for (int j = 0; j < 4; j++)
      priors[((size_t)(c2 * NT + t) * BB + bg + i) * LLn + o0 + og + j] = acc[i][j];
}

// ---------------- K4: dynamic routing — one wave per (b,c), barrier-free ----------------
__global__ __launch_bounds__(64) void k_route(const float* __restrict__ priors,
                                              const int* __restrict__ etp,
                                              float* __restrict__ h) {
  const int et = *etp;
  const int b = blockIdx.x >> 3;
  const int c2 = blockIdx.x & 7;
  const int lane = threadIdx.x;  // 0..63

  float pri[NT][4];
#pragma unroll
  for (int t = 0; t < NT; ++t) {
    if (t <= et) {
#pragma unroll
      for (int j = 0; j < 4; ++j)
        pri[t][j] = priors[((size_t)(c2 * NT + t) * BB + b) * LLn + j * 64 + lane];
    } else {
#pragma unroll
      for (int j = 0; j < 4; ++j) pri[t][j] = 0.f;
    }
  }

  float Lg[NT];
#pragma unroll
  for (int t = 0; t < NT; ++t) Lg[t] = 0.f;
  float vote[4] = {};

  for (int it = 0; it < 3; ++it) {
    float mx = -1e30f;
#pragma unroll
    for (int t = 0; t < NT; ++t)
      if (t <= et) mx = fmaxf(mx, Lg[t]);
    float p[NT];
    float s = 0.f;
#pragma unroll
    for (int t = 0; t < NT; ++t) {
      p[t] = (t <= et) ? __expf(Lg[t] - mx) : 0.f;
      s += p[t];
    }
    float inv = 1.f / s;
#pragma unroll
    for (int j = 0; j < 4; ++j) vote[j] = 0.f;
#pragma unroll
    for (int t = 0; t < NT; ++t) {
      if (t <= et) {
        float w = p[t] * inv;
#pragma unroll
        for (int j = 0; j < 4; ++j) vote[j] += w * pri[t][j];
      }
    }
    if (it == 2) break;

    float sq = vote[0] * vote[0] + vote[1] * vote[1] + vote[2] * vote[2] + vote[3] * vote[3];
#pragma unroll
    for (int st = 32; st > 0; st >>= 1) sq += __shfl_xor(sq, st, 64);
    sq += 1e-16f;
    float scale = (sq / (1.f + sq)) * rsqrtf(sq);

#pragma unroll
    for (int t = 0; t < NT; ++t) {
      if (t <= et) {
        float dot = pri[t][0] * vote[0] + pri[t][1] * vote[1] +
                    pri[t][2] * vote[2] + pri[t][3] * vote[3];
#pragma unroll
        for (int st = 32; st > 0; st >>= 1) dot += __shfl_xor(dot, st, 64);
        Lg[t] += scale * dot;
      }
    }
  }

#pragma unroll
  for (int j = 0; j < 4; ++j)
    h[((size_t)c2 * BB + b) * LLn + j * 64 + lane] = vote[j];
}

// ---------------- K5: out[b,l,d] = sum_c h[b,l,c]*lw[et][d][c] + lb[et][d] ----------------
__global__ __launch_bounds__(256) void k_out(const float* __restrict__ h,
                                             const float* __restrict__ lw,
                                             const float* __restrict__ lb,
                                             const int* __restrict__ etp,
                                             float* __restrict__ out) {
  int et = *etp;
  int row = blockIdx.x;  // b2*256 + l
  const float* hr = h + (size_t)row * CP;
  float hv[CP];
#pragma unroll
  for (int c = 0; c < CP; ++c) hv[c] = hr[c];
  const float* lwb = lw + (size_t)et * DD * CP;
  const float* lbb = lb + (size_t)et * DD;
  for (int d = threadIdx.x; d < DD; d += 256) {
    const float* w = lwb + (size_t)d * CP;
    float s2 = lbb[d];
#pragma unroll
    for (int c = 0; c < CP; ++c) s2 += hv[c] * w[c];
    out[(size_t)row * DD + d] = s2;
  }
}

extern "C" void kernel_launch(void* const* d_in, const int* in_sizes, int n_in,
                              void* d_out, int out_size, void* d_ws, size_t ws_size,
                              hipStream_t stream) {
  const float* x  = (const float*)d_in[0];
  const float* w1 = (const float*)d_in[1];
  const float* b1 = (const float*)d_in[2];
  const float* w2 = (const float*)d_in[3];
  const float* b2 = (const float*)d_in[4];
  const float* rw = (const float*)d_in[5];
  const float* lw = (const float*)d_in[6];
  const float* lb = (const float*)d_in[7];
  const int* etp  = (const int*)d_in[8];
  float* out = (float*)d_out;

  char* ws = (char*)d_ws;
  size_t off = 0;
  auto alloc = [&](size_t bytes) {
    void* p = ws + off;
    off = (off + bytes + 255) & ~(size_t)255;
    return p;
  };
  float* w12   = (float*)alloc((size_t)NT * CP * DI * 4);        // 245 KB
  float* b12   = (float*)alloc((size_t)NT * CP * 4);             // 320 B
  float* h2    = (float*)alloc((size_t)NT * BLr * CP * 4);       // 5.24 MB
  float* sems  = (float*)alloc((size_t)NT * BB * RR * 4);        // 5.24 MB
  float* priors= (float*)alloc((size_t)CP * NT * BB * LLn * 4);  // 5.24 MB
  float* hbuf  = (float*)alloc((size_t)CP * BB * LLn * 4);       // 0.52 MB

  k_w12<<<dim3(DI / 64, NT), 256, 0, stream>>>(w1, w2, w12);
  k_b12<<<20, 256, 0, stream>>>(b1, w2, b2, b12);
  k_fc<<<BLr / 16, 256, 0, stream>>>(x, w12, b12, h2);
  k_squash_sem<<<(BB * RR + 255) / 256, 256, 0, stream>>>(h2, etp, sems);
  k_priors<<<dim3(LLn / OT, NT, CP), 256, 0, stream>>>(sems, rw, etp, priors);
  k_route<<<BB * CP, 64, 0, stream>>>(priors, etp, hbuf);
  k_out<<<BLr, 256, 0, stream>>>(hbuf, lw, lb, etp, out);
}

// Round 4
// 855.628 us; speedup vs baseline: 1.0965x; 1.0206x over previous
//
#include <hip/hip_runtime.h>

constexpr int NT = 10;      // NTASKS
constexpr int CP = 8;       // CAP
constexpr int LLn = 256;    // L
constexpr int DI = 768;     // D_IN
constexpr int DD = 768;     // D_DOWN
constexpr int BB = 64;      // B
constexpr int BLr = BB * LLn;   // 16384
constexpr int RR = LLn * CP;    // 2048

// ---------------- K_W12: W12[t*8+c][i] = sum_d w1[t][d][i] * w2[t][c][d] ----------------
__global__ __launch_bounds__(256) void k_w12(const float* __restrict__ w1,
                                             const float* __restrict__ w2,
                                             float* __restrict__ w12) {
  const int t = blockIdx.y;
  const int i0 = blockIdx.x * 64;
  __shared__ float sW1[64][68];   // [d_local][i_local], stride 68 (16B-aligned, conflict-safe)
  __shared__ float sW2[CP][64];   // [c][d_local]
  const int tid = threadIdx.x;
  const int il = tid >> 2;        // 0..63
  const int cc = (tid & 3) * 2;   // c pair
  float a0 = 0.f, a1 = 0.f;
  for (int d0 = 0; d0 < DD; d0 += 64) {
#pragma unroll
    for (int p = 0; p < 4; p++) {
      int idx = p * 256 + tid;
      int dl = idx >> 4, c4 = (idx & 15) * 4;
      *(float4*)&sW1[dl][c4] =
          *(const float4*)(w1 + ((size_t)t * DD + d0 + dl) * DI + i0 + c4);
    }
    if (tid < 128) {
      int c = tid >> 4, d4 = (tid & 15) * 4;
      *(float4*)&sW2[c][d4] =
          *(const float4*)(w2 + ((size_t)t * CP + c) * DD + d0 + d4);
    }
    __syncthreads();
#pragma unroll 16
    for (int dl = 0; dl < 64; ++dl) {
      float v = sW1[dl][il];
      a0 += v * sW2[cc][dl];
      a1 += v * sW2[cc + 1][dl];
    }
    __syncthreads();
  }
  w12[((size_t)t * CP + cc) * DI + i0 + il]     = a0;
  w12[((size_t)t * CP + cc + 1) * DI + i0 + il] = a1;
}

// ---------------- K_B12: b12[t*8+c] = sum_d b1[t][d]*w2[t][c][d] + b2[t][c] ----------------
__global__ __launch_bounds__(256) void k_b12(const float* __restrict__ b1,
                                             const float* __restrict__ w2,
                                             const float* __restrict__ b2,
                                             float* __restrict__ b12) {
  const int tc = blockIdx.x * 4 + (threadIdx.x >> 6);  // 0..79
  const int lane = threadIdx.x & 63;
  const int t = tc >> 3, c = tc & 7;
  const float* b1r = b1 + (size_t)t * DD;
  const float* w2r = w2 + ((size_t)t * CP + c) * DD;
  float s = 0.f;
  for (int d = lane * 4; d < DD; d += 256) {  // 3 iters
    float4 bv = *(const float4*)(b1r + d);
    float4 wv = *(const float4*)(w2r + d);
    s += bv.x * wv.x + bv.y * wv.y + bv.z * wv.z + bv.w * wv.w;
  }
#pragma unroll
  for (int st = 32; st > 0; st >>= 1) s += __shfl_xor(s, st, 64);
  if (lane == 0) b12[tc] = s + b2[t * CP + c];
}

// ---------------- K_FC: h2[t][m][c] = sum_i x[m][i]*W12[n][i] + b12 ----------------
// GEMM M=16384, N=80, K=768. Key: n-set is WAVE-UNIFORM (lanes = m-rows), so all
// w12 loads are uniform-address -> scalar (SGPR) loads / 1-line broadcasts.
// Round-3 failure mode (5 scattered per-lane w loads = 16 lines each, 3.9 GB from
// L2) is eliminated: w traffic ~16 MB. No LDS, no barriers. acc[10]+addr ~ 40 VGPR.
// Grid = 64 m-blocks x 8 n-groups = 512 blocks = 2 blocks/CU = 2 waves/SIMD.
__global__ __launch_bounds__(256) void k_fc(const float* __restrict__ x,
                                            const float* __restrict__ w12,
                                            const float* __restrict__ b12,
                                            float* __restrict__ h2) {
  const int n0 = blockIdx.y * 10;                      // wave-uniform n decade
  const int m = blockIdx.x * 256 + threadIdx.x;        // per-lane m-row
  const float4* xr = (const float4*)(x + (size_t)m * DI);
  const float4* wr = (const float4*)w12;
  float acc[10] = {};
#pragma unroll 2
  for (int i4 = 0; i4 < DI / 4; ++i4) {
    float4 xv = xr[i4];                                // per-lane (own row, L1-friendly)
#pragma unroll
    for (int j = 0; j < 10; ++j) {
      float4 wv = wr[(size_t)(n0 + j) * (DI / 4) + i4];  // uniform -> s_load/broadcast
      acc[j] += xv.x * wv.x + xv.y * wv.y + xv.z * wv.z + xv.w * wv.w;
    }
  }
#pragma unroll
  for (int j = 0; j < 10; ++j) {
    int n = n0 + j;
    int t = n >> 3, c = n & 7;
    h2[((size_t)t * BLr + m) * CP + c] = acc[j] + b12[n];
  }
}

// ---------------- K2: squash over task dim -> sems[t][b][r] (t<=et) ----------------
__global__ __launch_bounds__(256) void k_squash_sem(const float* __restrict__ h2,
                                                    const int* __restrict__ etp,
                                                    float* __restrict__ sems) {
  int et = *etp;
  int i = blockIdx.x * 256 + threadIdx.x;  // i = b*2048 + r
  if (i >= BB * RR) return;
  float v[NT];
  float sq = 0.f;
#pragma unroll
  for (int t = 0; t < NT; ++t) {
    v[t] = h2[(size_t)t * BB * RR + i];
    sq += v[t] * v[t];
  }
  sq += 1e-16f;
  float scale = (sq / (1.f + sq)) * rsqrtf(sq);
#pragma unroll
  for (int t = 0; t < NT; ++t)
    if (t <= et) sems[(size_t)t * BB * RR + i] = scale * v[t];
}

// ---------------- K3: priors[c][t][b][o] = sum_r sems[t][b][r] * rw[c][t][r][o] ----------------
// Same uniform-operand structure as k_fc: lanes = o (rw reads stride-1 coalesced),
// b-set wave-uniform (sems loads scalar/broadcast). No LDS, no barriers.
// Block: 256 thr = o-half (128 o) x 2 b-subgroups of 8. Grid.x = 2 o-halves x 4
// b-groups; grid = 8 x 10 x 8 = 640 blocks (384 active) = 1.5 waves/SIMD.
// Per r4 per thread: 4 coalesced b32 (rw) + 8 uniform 16B (sems) + 32 FMA.
__global__ __launch_bounds__(256) void k_priors(const float* __restrict__ sems,
                                                const float* __restrict__ rw,
                                                const int* __restrict__ etp,
                                                float* __restrict__ priors) {
  const int et = *etp;
  const int t = blockIdx.y;
  if (t > et) return;
  const int c2 = blockIdx.z;
  const int bgrp = blockIdx.x & 3;        // b-group of 16
  const int oh = blockIdx.x >> 2;         // o half
  const int o = oh * 128 + (threadIdx.x & 127);
  const int b0 = bgrp * 16 + (threadIdx.x >> 7) * 8;  // this thread's 8 b's

  const float* rwp = rw + ((size_t)(c2 * NT + t) * RR) * LLn + o;
  const float* semp = sems + ((size_t)t * BB + b0) * RR;

  float acc[8] = {};
#pragma unroll 2
  for (int r = 0; r < RR; r += 4) {
    float rv[4];
#pragma unroll
    for (int rr = 0; rr < 4; ++rr) rv[rr] = rwp[(size_t)(r + rr) * LLn];
#pragma unroll
    for (int b = 0; b < 8; ++b) {
      float4 sv = *(const float4*)(semp + (size_t)b * RR + r);  // uniform
      acc[b] += sv.x * rv[0] + sv.y * rv[1] + sv.z * rv[2] + sv.w * rv[3];
    }
  }
#pragma unroll
  for (int b = 0; b < 8; ++b)
    priors[((size_t)(c2 * NT + t) * BB + b0 + b) * LLn + o] = acc[b];
}

// ---------------- K4: dynamic routing — one wave per (b,c), barrier-free ----------------
__global__ __launch_bounds__(64) void k_route(const float* __restrict__ priors,
                                              const int* __restrict__ etp,
                                              float* __restrict__ h) {
  const int et = *etp;
  const int b = blockIdx.x >> 3;
  const int c2 = blockIdx.x & 7;
  const int lane = threadIdx.x;  // 0..63

  float pri[NT][4];
#pragma unroll
  for (int t = 0; t < NT; ++t) {
    if (t <= et) {
#pragma unroll
      for (int j = 0; j < 4; ++j)
        pri[t][j] = priors[((size_t)(c2 * NT + t) * BB + b) * LLn + j * 64 + lane];
    } else {
#pragma unroll
      for (int j = 0; j < 4; ++j) pri[t][j] = 0.f;
    }
  }

  float Lg[NT];
#pragma unroll
  for (int t = 0; t < NT; ++t) Lg[t] = 0.f;
  float vote[4] = {};

  for (int it = 0; it < 3; ++it) {
    float mx = -1e30f;
#pragma unroll
    for (int t = 0; t < NT; ++t)
      if (t <= et) mx = fmaxf(mx, Lg[t]);
    float p[NT];
    float s = 0.f;
#pragma unroll
    for (int t = 0; t < NT; ++t) {
      p[t] = (t <= et) ? __expf(Lg[t] - mx) : 0.f;
      s += p[t];
    }
    float inv = 1.f / s;
#pragma unroll
    for (int j = 0; j < 4; ++j) vote[j] = 0.f;
#pragma unroll
    for (int t = 0; t < NT; ++t) {
      if (t <= et) {
        float w = p[t] * inv;
#pragma unroll
        for (int j = 0; j < 4; ++j) vote[j] += w * pri[t][j];
      }
    }
    if (it == 2) break;

    float sq = vote[0] * vote[0] + vote[1] * vote[1] + vote[2] * vote[2] + vote[3] * vote[3];
#pragma unroll
    for (int st = 32; st > 0; st >>= 1) sq += __shfl_xor(sq, st, 64);
    sq += 1e-16f;
    float scale = (sq / (1.f + sq)) * rsqrtf(sq);

#pragma unroll
    for (int t = 0; t < NT; ++t) {
      if (t <= et) {
        float dot = pri[t][0] * vote[0] + pri[t][1] * vote[1] +
                    pri[t][2] * vote[2] + pri[t][3] * vote[3];
#pragma unroll
        for (int st = 32; st > 0; st >>= 1) dot += __shfl_xor(dot, st, 64);
        Lg[t] += scale * dot;
      }
    }
  }

#pragma unroll
  for (int j = 0; j < 4; ++j)
    h[((size_t)c2 * BB + b) * LLn + j * 64 + lane] = vote[j];
}

// ---------------- K5: out[b,l,d] = sum_c h[b,l,c]*lw[et][d][c] + lb[et][d] ----------------
__global__ __launch_bounds__(256) void k_out(const float* __restrict__ h,
                                             const float* __restrict__ lw,
                                             const float* __restrict__ lb,
                                             const int* __restrict__ etp,
                                             float* __restrict__ out) {
  int et = *etp;
  int row = blockIdx.x;  // b2*256 + l
  const float* hr = h + (size_t)row * CP;
  float hv[CP];
#pragma unroll
  for (int c = 0; c < CP; ++c) hv[c] = hr[c];
  const float* lwb = lw + (size_t)et * DD * CP;
  const float* lbb = lb + (size_t)et * DD;
  for (int d = threadIdx.x; d < DD; d += 256) {
    const float* w = lwb + (size_t)d * CP;
    float s2 = lbb[d];
#pragma unroll
    for (int c = 0; c < CP; ++c) s2 += hv[c] * w[c];
    out[(size_t)row * DD + d] = s2;
  }
}

extern "C" void kernel_launch(void* const* d_in, const int* in_sizes, int n_in,
                              void* d_out, int out_size, void* d_ws, size_t ws_size,
                              hipStream_t stream) {
  const float* x  = (const float*)d_in[0];
  const float* w1 = (const float*)d_in[1];
  const float* b1 = (const float*)d_in[2];
  const float* w2 = (const float*)d_in[3];
  const float* b2 = (const float*)d_in[4];
  const float* rw = (const float*)d_in[5];
  const float* lw = (const float*)d_in[6];
  const float* lb = (const float*)d_in[7];
  const int* etp  = (const int*)d_in[8];
  float* out = (float*)d_out;

  char* ws = (char*)d_ws;
  size_t off = 0;
  auto alloc = [&](size_t bytes) {
    void* p = ws + off;
    off = (off + bytes + 255) & ~(size_t)255;
    return p;
  };
  float* w12   = (float*)alloc((size_t)NT * CP * DI * 4);        // 245 KB
  float* b12   = (float*)alloc((size_t)NT * CP * 4);             // 320 B
  float* h2    = (float*)alloc((size_t)NT * BLr * CP * 4);       // 5.24 MB
  float* sems  = (float*)alloc((size_t)NT * BB * RR * 4);        // 5.24 MB
  float* priors= (float*)alloc((size_t)CP * NT * BB * LLn * 4);  // 5.24 MB
  float* hbuf  = (float*)alloc((size_t)CP * BB * LLn * 4);       // 0.52 MB

  k_w12<<<dim3(DI / 64, NT), 256, 0, stream>>>(w1, w2, w12);
  k_b12<<<20, 256, 0, stream>>>(b1, w2, b2, b12);
  k_fc<<<dim3(BLr / 256, 8), 256, 0, stream>>>(x, w12, b12, h2);
  k_squash_sem<<<(BB * RR + 255) / 256, 256, 0, stream>>>(h2, etp, sems);
  k_priors<<<dim3(8, NT, CP), 256, 0, stream>>>(sems, rw, etp, priors);
  k_route<<<BB * CP, 64, 0, stream>>>(priors, etp, hbuf);
  k_out<<<BLr, 256, 0, stream>>>(hbuf, lw, lb, etp, out);
}

// Round 5
// 556.922 us; speedup vs baseline: 1.6847x; 1.5364x over previous
//
#include <hip/hip_runtime.h>

constexpr int NT = 10;      // NTASKS
constexpr int CP = 8;       // CAP
constexpr int LLn = 256;    // L
constexpr int DI = 768;     // D_IN
constexpr int DD = 768;     // D_DOWN
constexpr int BB = 64;      // B
constexpr int BLr = BB * LLn;   // 16384
constexpr int RR = LLn * CP;    // 2048
constexpr int KSPLIT = 8;       // k_priors r-split
constexpr int RCH = RR / KSPLIT;            // 256
constexpr size_t PRSZ = (size_t)CP * NT * BB * LLn;  // priors elements (1.31M)

// ---------------- K_W12: W12[t*8+c][i] = sum_d w1[t][d][i] * w2[t][c][d] ----------------
__global__ __launch_bounds__(256) void k_w12(const float* __restrict__ w1,
                                             const float* __restrict__ w2,
                                             float* __restrict__ w12) {
  const int t = blockIdx.y;
  const int i0 = blockIdx.x * 64;
  __shared__ float sW1[64][68];
  __shared__ float sW2[CP][64];
  const int tid = threadIdx.x;
  const int il = tid >> 2;
  const int cc = (tid & 3) * 2;
  float a0 = 0.f, a1 = 0.f;
  for (int d0 = 0; d0 < DD; d0 += 64) {
#pragma unroll
    for (int p = 0; p < 4; p++) {
      int idx = p * 256 + tid;
      int dl = idx >> 4, c4 = (idx & 15) * 4;
      *(float4*)&sW1[dl][c4] =
          *(const float4*)(w1 + ((size_t)t * DD + d0 + dl) * DI + i0 + c4);
    }
    if (tid < 128) {
      int c = tid >> 4, d4 = (tid & 15) * 4;
      *(float4*)&sW2[c][d4] =
          *(const float4*)(w2 + ((size_t)t * CP + c) * DD + d0 + d4);
    }
    __syncthreads();
#pragma unroll 16
    for (int dl = 0; dl < 64; ++dl) {
      float v = sW1[dl][il];
      a0 += v * sW2[cc][dl];
      a1 += v * sW2[cc + 1][dl];
    }
    __syncthreads();
  }
  w12[((size_t)t * CP + cc) * DI + i0 + il]     = a0;
  w12[((size_t)t * CP + cc + 1) * DI + i0 + il] = a1;
}

// ---------------- K_B12 ----------------
__global__ __launch_bounds__(256) void k_b12(const float* __restrict__ b1,
                                             const float* __restrict__ w2,
                                             const float* __restrict__ b2,
                                             float* __restrict__ b12) {
  const int tc = blockIdx.x * 4 + (threadIdx.x >> 6);  // 0..79
  const int lane = threadIdx.x & 63;
  const int t = tc >> 3, c = tc & 7;
  const float* b1r = b1 + (size_t)t * DD;
  const float* w2r = w2 + ((size_t)t * CP + c) * DD;
  float s = 0.f;
  for (int d = lane * 4; d < DD; d += 256) {
    float4 bv = *(const float4*)(b1r + d);
    float4 wv = *(const float4*)(w2r + d);
    s += bv.x * wv.x + bv.y * wv.y + bv.z * wv.z + bv.w * wv.w;
  }
#pragma unroll
  for (int st = 32; st > 0; st >>= 1) s += __shfl_xor(s, st, 64);
  if (lane == 0) b12[tc] = s + b2[t * CP + c];
}

// ---------------- K_FC: wave-uniform n decade (w12 loads scalarize) ----------------
__global__ __launch_bounds__(256) void k_fc(const float* __restrict__ x,
                                            const float* __restrict__ w12,
                                            const float* __restrict__ b12,
                                            float* __restrict__ h2) {
  const int n0 = blockIdx.y * 10;
  const int m = blockIdx.x * 256 + threadIdx.x;
  const float4* xr = (const float4*)(x + (size_t)m * DI);
  const float4* wr = (const float4*)w12;
  float acc[10] = {};
#pragma unroll 2
  for (int i4 = 0; i4 < DI / 4; ++i4) {
    float4 xv = xr[i4];
#pragma unroll
    for (int j = 0; j < 10; ++j) {
      float4 wv = wr[(size_t)(n0 + j) * (DI / 4) + i4];
      acc[j] += xv.x * wv.x + xv.y * wv.y + xv.z * wv.z + xv.w * wv.w;
    }
  }
#pragma unroll
  for (int j = 0; j < 10; ++j) {
    int n = n0 + j;
    int t = n >> 3, c = n & 7;
    h2[((size_t)t * BLr + m) * CP + c] = acc[j] + b12[n];
  }
}

// ---------------- K2: squash over task dim -> sems[t][b][r] (t<=et) ----------------
__global__ __launch_bounds__(256) void k_squash_sem(const float* __restrict__ h2,
                                                    const int* __restrict__ etp,
                                                    float* __restrict__ sems) {
  int et = *etp;
  int i = blockIdx.x * 256 + threadIdx.x;  // i = b*2048 + r
  if (i >= BB * RR) return;
  float v[NT];
  float sq = 0.f;
#pragma unroll
  for (int t = 0; t < NT; ++t) {
    v[t] = h2[(size_t)t * BB * RR + i];
    sq += v[t] * v[t];
  }
  sq += 1e-16f;
  float scale = (sq / (1.f + sq)) * rsqrtf(sq);
#pragma unroll
  for (int t = 0; t < NT; ++t)
    if (t <= et) sems[(size_t)t * BB * RR + i] = scale * v[t];
}

// ---------------- K_SEMT: semsT[t][r][b] = sems[t][b][r] (LDS tile transpose) ----------------
__global__ __launch_bounds__(256) void k_semT(const float* __restrict__ sems,
                                              const int* __restrict__ etp,
                                              float* __restrict__ semsT) {
  const int t = blockIdx.y;
  if (t > *etp) return;
  const int r0 = blockIdx.x * 64;
  __shared__ float tile[64][65];
  const int tid = threadIdx.x;
  {
    const int rl = tid & 63;       // lanes = r (coalesced read)
    const int bq = tid >> 6;
#pragma unroll
    for (int i = 0; i < 16; ++i) {
      int b = bq * 16 + i;
      tile[b][rl] = sems[((size_t)t * BB + b) * RR + r0 + rl];
    }
  }
  __syncthreads();
  {
    const int bl = tid & 63;       // lanes = b (coalesced write)
    const int rq = tid >> 6;
#pragma unroll
    for (int i = 0; i < 16; ++i) {
      int r = rq * 16 + i;
      semsT[((size_t)t * RR + r0 + r) * BB + bl] = tile[bl][r];
    }
  }
}

// ---------------- K3: priors partials, K-split GEMM ----------------
// Per (c,t,kc) block: 4 waves, wave = 16 b x 256 o (acc[16] float4).
// Per r: 1 coalesced rw dwordx4 (1KB/wave) + 4 uniform sems dwordx4 + 64 FMA.
// rw fetched exactly once globally; K-split x8 gives ~2 waves/SIMD.
__global__ __launch_bounds__(256) void k_priors(const float* __restrict__ semsT,
                                                const float* __restrict__ rw,
                                                const int* __restrict__ etp,
                                                float* __restrict__ pbuf) {
  const int et = *etp;
  const int t = blockIdx.y;
  if (t > et) return;
  const int c2 = blockIdx.z;
  const int kc = blockIdx.x;           // r-chunk
  const int lane = threadIdx.x & 63;
  const int wv = threadIdx.x >> 6;     // wave 0..3
  const int b0 = wv * 16;
  const int o4 = lane * 4;
  const int r0 = kc * RCH;

  const float* rwp = rw + ((size_t)(c2 * NT + t) * RR + r0) * LLn + o4;
  const float* sp  = semsT + ((size_t)t * RR + r0) * BB + b0;

  float4 acc[16];
#pragma unroll
  for (int i = 0; i < 16; ++i) acc[i] = float4{0.f, 0.f, 0.f, 0.f};

#pragma unroll 2
  for (int r = 0; r < RCH; ++r) {
    float4 rv = *(const float4*)(rwp + (size_t)r * LLn);
    float4 s0 = *(const float4*)(sp + (size_t)r * BB + 0);
    float4 s1 = *(const float4*)(sp + (size_t)r * BB + 4);
    float4 s2 = *(const float4*)(sp + (size_t)r * BB + 8);
    float4 s3 = *(const float4*)(sp + (size_t)r * BB + 12);
    float sv[16] = {s0.x, s0.y, s0.z, s0.w, s1.x, s1.y, s1.z, s1.w,
                    s2.x, s2.y, s2.z, s2.w, s3.x, s3.y, s3.z, s3.w};
#pragma unroll
    for (int b = 0; b < 16; ++b) {
      acc[b].x += sv[b] * rv.x;
      acc[b].y += sv[b] * rv.y;
      acc[b].z += sv[b] * rv.z;
      acc[b].w += sv[b] * rv.w;
    }
  }

#pragma unroll
  for (int b = 0; b < 16; ++b) {
    size_t idx = ((size_t)kc * PRSZ) +
                 (((size_t)(c2 * NT + t) * BB + b0 + b) * LLn + o4);
    *(float4*)(pbuf + idx) = acc[b];
  }
}

// ---------------- K_PSUM: priors = sum over KSPLIT partials ----------------
__global__ __launch_bounds__(256) void k_psum(const float* __restrict__ pbuf,
                                              float* __restrict__ priors) {
  size_t i = ((size_t)blockIdx.x * 256 + threadIdx.x) * 4;
  float4 s = {0.f, 0.f, 0.f, 0.f};
#pragma unroll
  for (int k = 0; k < KSPLIT; ++k) {
    float4 v = *(const float4*)(pbuf + (size_t)k * PRSZ + i);
    s.x += v.x; s.y += v.y; s.z += v.z; s.w += v.w;
  }
  *(float4*)(priors + i) = s;
}

// ---------------- K4: dynamic routing — one wave per (b,c), barrier-free ----------------
__global__ __launch_bounds__(64) void k_route(const float* __restrict__ priors,
                                              const int* __restrict__ etp,
                                              float* __restrict__ h) {
  const int et = *etp;
  const int b = blockIdx.x >> 3;
  const int c2 = blockIdx.x & 7;
  const int lane = threadIdx.x;

  float pri[NT][4];
#pragma unroll
  for (int t = 0; t < NT; ++t) {
    if (t <= et) {
#pragma unroll
      for (int j = 0; j < 4; ++j)
        pri[t][j] = priors[((size_t)(c2 * NT + t) * BB + b) * LLn + j * 64 + lane];
    } else {
#pragma unroll
      for (int j = 0; j < 4; ++j) pri[t][j] = 0.f;
    }
  }

  float Lg[NT];
#pragma unroll
  for (int t = 0; t < NT; ++t) Lg[t] = 0.f;
  float vote[4] = {};

  for (int it = 0; it < 3; ++it) {
    float mx = -1e30f;
#pragma unroll
    for (int t = 0; t < NT; ++t)
      if (t <= et) mx = fmaxf(mx, Lg[t]);
    float p[NT];
    float s = 0.f;
#pragma unroll
    for (int t = 0; t < NT; ++t) {
      p[t] = (t <= et) ? __expf(Lg[t] - mx) : 0.f;
      s += p[t];
    }
    float inv = 1.f / s;
#pragma unroll
    for (int j = 0; j < 4; ++j) vote[j] = 0.f;
#pragma unroll
    for (int t = 0; t < NT; ++t) {
      if (t <= et) {
        float w = p[t] * inv;
#pragma unroll
        for (int j = 0; j < 4; ++j) vote[j] += w * pri[t][j];
      }
    }
    if (it == 2) break;

    float sq = vote[0] * vote[0] + vote[1] * vote[1] + vote[2] * vote[2] + vote[3] * vote[3];
#pragma unroll
    for (int st = 32; st > 0; st >>= 1) sq += __shfl_xor(sq, st, 64);
    sq += 1e-16f;
    float scale = (sq / (1.f + sq)) * rsqrtf(sq);

#pragma unroll
    for (int t = 0; t < NT; ++t) {
      if (t <= et) {
        float dot = pri[t][0] * vote[0] + pri[t][1] * vote[1] +
                    pri[t][2] * vote[2] + pri[t][3] * vote[3];
#pragma unroll
        for (int st = 32; st > 0; st >>= 1) dot += __shfl_xor(dot, st, 64);
        Lg[t] += scale * dot;
      }
    }
  }

#pragma unroll
  for (int j = 0; j < 4; ++j)
    h[((size_t)c2 * BB + b) * LLn + j * 64 + lane] = vote[j];
}

// ---------------- K5: out[b,l,d] = sum_c h[b,l,c]*lw[et][d][c] + lb[et][d] ----------------
__global__ __launch_bounds__(256) void k_out(const float* __restrict__ h,
                                             const float* __restrict__ lw,
                                             const float* __restrict__ lb,
                                             const int* __restrict__ etp,
                                             float* __restrict__ out) {
  int et = *etp;
  int row = blockIdx.x;
  const float* hr = h + (size_t)row * CP;
  float hv[CP];
#pragma unroll
  for (int c = 0; c < CP; ++c) hv[c] = hr[c];
  const float* lwb = lw + (size_t)et * DD * CP;
  const float* lbb = lb + (size_t)et * DD;
  for (int d = threadIdx.x; d < DD; d += 256) {
    const float* w = lwb + (size_t)d * CP;
    float s2 = lbb[d];
#pragma unroll
    for (int c = 0; c < CP; ++c) s2 += hv[c] * w[c];
    out[(size_t)row * DD + d] = s2;
  }
}

extern "C" void kernel_launch(void* const* d_in, const int* in_sizes, int n_in,
                              void* d_out, int out_size, void* d_ws, size_t ws_size,
                              hipStream_t stream) {
  const float* x  = (const float*)d_in[0];
  const float* w1 = (const float*)d_in[1];
  const float* b1 = (const float*)d_in[2];
  const float* w2 = (const float*)d_in[3];
  const float* b2 = (const float*)d_in[4];
  const float* rw = (const float*)d_in[5];
  const float* lw = (const float*)d_in[6];
  const float* lb = (const float*)d_in[7];
  const int* etp  = (const int*)d_in[8];
  float* out = (float*)d_out;

  char* ws = (char*)d_ws;
  size_t off = 0;
  auto alloc = [&](size_t bytes) {
    void* p = ws + off;
    off = (off + bytes + 255) & ~(size_t)255;
    return p;
  };
  float* w12   = (float*)alloc((size_t)NT * CP * DI * 4);        // 245 KB
  float* b12   = (float*)alloc((size_t)NT * CP * 4);             // 320 B
  float* h2    = (float*)alloc((size_t)NT * BLr * CP * 4);       // 5.24 MB
  float* sems  = (float*)alloc((size_t)NT * BB * RR * 4);        // 5.24 MB
  float* semsT = (float*)alloc((size_t)NT * BB * RR * 4);        // 5.24 MB
  float* priors= (float*)alloc(PRSZ * 4);                        // 5.24 MB
  float* pbuf  = (float*)alloc((size_t)KSPLIT * PRSZ * 4);       // 41.9 MB
  float* hbuf  = (float*)alloc((size_t)CP * BB * LLn * 4);       // 0.52 MB

  k_w12<<<dim3(DI / 64, NT), 256, 0, stream>>>(w1, w2, w12);
  k_b12<<<20, 256, 0, stream>>>(b1, w2, b2, b12);
  k_fc<<<dim3(BLr / 256, 8), 256, 0, stream>>>(x, w12, b12, h2);
  k_squash_sem<<<(BB * RR + 255) / 256, 256, 0, stream>>>(h2, etp, sems);
  k_semT<<<dim3(RR / 64, NT), 256, 0, stream>>>(sems, etp, semsT);
  k_priors<<<dim3(KSPLIT, NT, CP), 256, 0, stream>>>(semsT, rw, etp, pbuf);
  k_psum<<<(int)(PRSZ / 1024), 256, 0, stream>>>(pbuf, priors);
  k_route<<<BB * CP, 64, 0, stream>>>(priors, etp, hbuf);
  k_out<<<BLr, 256, 0, stream>>>(hbuf, lw, lb, etp, out);
}